// Round 6
// baseline (224.091 us; speedup 1.0000x reference)
//
#include <hip/hip_runtime.h>
#include <math.h>

// B=65536 rows, N=1024 cols, fp32.
//   t_b = argmax_c target[b,c]  (first-max tie-break)
//   out = mean_b(-log(y[b,t_b]+1e-8)) + sum_{b,c} w[popc(t_b^c)]*y[b,c]/(B*N),  w[p]=(p==0)?0:6^p
// R5 lesson: 4-row batch spilled (WRITE_SIZE 262MB). R6: single-row stages with
// double-buffered target prefetch -> only 32 data VGPRs live, loads in flight through
// amax+chain+wsum. __launch_bounds__(256,8) for 8 waves/SIMD. Atomic finish, no reduce kernel.

#define B_ROWS 65536
#define N_COLS 1024
#define WAVES_PER_BLOCK 4
#define ROWS_BLOCKS 2048
#define ROWS_THREADS 256
#define NWAVES (ROWS_BLOCKS * WAVES_PER_BLOCK)  // 8192 waves -> 8 rows/wave

__device__ __forceinline__ void amax16(float4 v0, float4 v1, float4 v2, float4 v3,
                                       int lane, float& bv, int& bi) {
    // ascending-column scan, strict > = first-index semantics within the lane
    bv = -1.0f; bi = 0;
    const int c0 = 4 * lane, c1 = 4 * (lane + 64), c2 = 4 * (lane + 128), c3 = 4 * (lane + 192);
    if (v0.x > bv) { bv = v0.x; bi = c0;     }
    if (v0.y > bv) { bv = v0.y; bi = c0 + 1; }
    if (v0.z > bv) { bv = v0.z; bi = c0 + 2; }
    if (v0.w > bv) { bv = v0.w; bi = c0 + 3; }
    if (v1.x > bv) { bv = v1.x; bi = c1;     }
    if (v1.y > bv) { bv = v1.y; bi = c1 + 1; }
    if (v1.z > bv) { bv = v1.z; bi = c1 + 2; }
    if (v1.w > bv) { bv = v1.w; bi = c1 + 3; }
    if (v2.x > bv) { bv = v2.x; bi = c2;     }
    if (v2.y > bv) { bv = v2.y; bi = c2 + 1; }
    if (v2.z > bv) { bv = v2.z; bi = c2 + 2; }
    if (v2.w > bv) { bv = v2.w; bi = c2 + 3; }
    if (v3.x > bv) { bv = v3.x; bi = c3;     }
    if (v3.y > bv) { bv = v3.y; bi = c3 + 1; }
    if (v3.z > bv) { bv = v3.z; bi = c3 + 2; }
    if (v3.w > bv) { bv = v3.w; bi = c3 + 3; }
}

__device__ __forceinline__ int chain_argmax(float bv, int bi) {
    #pragma unroll
    for (int m = 32; m >= 1; m >>= 1) {
        const float ov = __shfl_xor(bv, m, 64);
        const int   oi = __shfl_xor(bi, m, 64);
        if (ov > bv || (ov == bv && oi < bi)) { bv = ov; bi = oi; }
    }
    return bi;
}

__device__ __forceinline__ float pick16(float4 v0, float4 v1, float4 v2, float4 v3, int t) {
    const int k = t >> 8;   // which float4 within the owning lane
    const int e = t & 3;
    float4 s = (k & 2) ? ((k & 1) ? v3 : v2) : ((k & 1) ? v1 : v0);
    return (e & 2) ? ((e & 1) ? s.w : s.z) : ((e & 1) ? s.y : s.x);
}

__global__ __launch_bounds__(ROWS_THREADS, 8)
void ce_rows_kernel(const float* __restrict__ y_true,
                    const float* __restrict__ target,
                    float* __restrict__ out) {
    __shared__ float w_lds[16];
    __shared__ float wave_part[WAVES_PER_BLOCK];

    const int tid = threadIdx.x;
    if (tid < 16) {
        float w = 1.0f;
        for (int p = 0; p < tid; ++p) w *= 6.0f;   // exact: 6^10 < 2^26
        w_lds[tid] = (tid == 0) ? 0.0f : w;
    }
    __syncthreads();

    const int lane  = tid & 63;
    const int wid   = tid >> 6;
    const int gwave = blockIdx.x * WAVES_PER_BLOCK + wid;

    float acc_pt = 0.0f;   // lane-private weighted-sum partial
    float acc_lg = 0.0f;   // lane-private sum of log(y[t]+1e-8), owner lanes only

    // prologue: prefetch target row for stage 0 into buffer A
    const float4* tp = (const float4*)(target + (size_t)gwave * N_COLS);
    float4 tA0 = tp[lane], tA1 = tp[lane + 64], tA2 = tp[lane + 128], tA3 = tp[lane + 192];
    float4 tB0, tB1, tB2, tB3;

    #pragma unroll 1
    for (int s = 0; s < 8; s += 2) {
        // ---------- stage A: row s (target already in tA) ----------
        {
            const int row = gwave + s * NWAVES;
            const float4* yp = (const float4*)(y_true + (size_t)row * N_COLS);
            float4 y0 = yp[lane], y1 = yp[lane + 64], y2 = yp[lane + 128], y3 = yp[lane + 192];
            float bv; int bi;
            amax16(tA0, tA1, tA2, tA3, lane, bv, bi);      // waits tA; y in flight
            // prefetch target row s+1 into B (in flight through chain+wsum)
            const float4* tn = (const float4*)(target + (size_t)(row + NWAVES) * N_COLS);
            tB0 = tn[lane]; tB1 = tn[lane + 64]; tB2 = tn[lane + 128]; tB3 = tn[lane + 192];
            const int t = chain_argmax(bv, bi);            // 6 shuffles; loads in flight
            const int x0 = t ^ (4 * lane), x1 = t ^ (4 * (lane + 64));
            const int x2 = t ^ (4 * (lane + 128)), x3 = t ^ (4 * (lane + 192));
            acc_pt += w_lds[__popc(x0)]     * y0.x + w_lds[__popc(x0 ^ 1)] * y0.y
                    + w_lds[__popc(x0 ^ 2)] * y0.z + w_lds[__popc(x0 ^ 3)] * y0.w
                    + w_lds[__popc(x1)]     * y1.x + w_lds[__popc(x1 ^ 1)] * y1.y
                    + w_lds[__popc(x1 ^ 2)] * y1.z + w_lds[__popc(x1 ^ 3)] * y1.w
                    + w_lds[__popc(x2)]     * y2.x + w_lds[__popc(x2 ^ 1)] * y2.y
                    + w_lds[__popc(x2 ^ 2)] * y2.z + w_lds[__popc(x2 ^ 3)] * y2.w
                    + w_lds[__popc(x3)]     * y3.x + w_lds[__popc(x3 ^ 1)] * y3.y
                    + w_lds[__popc(x3 ^ 2)] * y3.z + w_lds[__popc(x3 ^ 3)] * y3.w;
            if (((t >> 2) & 63) == lane)
                acc_lg += logf(pick16(y0, y1, y2, y3, t) + 1e-8f);
        }
        // ---------- stage B: row s+1 (target already in tB) ----------
        {
            const int row = gwave + (s + 1) * NWAVES;
            const float4* yp = (const float4*)(y_true + (size_t)row * N_COLS);
            float4 y0 = yp[lane], y1 = yp[lane + 64], y2 = yp[lane + 128], y3 = yp[lane + 192];
            float bv; int bi;
            amax16(tB0, tB1, tB2, tB3, lane, bv, bi);
            if (s < 6) {   // prefetch target row s+2 into A (wave-uniform branch)
                const float4* tn = (const float4*)(target + (size_t)(row + NWAVES) * N_COLS);
                tA0 = tn[lane]; tA1 = tn[lane + 64]; tA2 = tn[lane + 128]; tA3 = tn[lane + 192];
            }
            const int t = chain_argmax(bv, bi);
            const int x0 = t ^ (4 * lane), x1 = t ^ (4 * (lane + 64));
            const int x2 = t ^ (4 * (lane + 128)), x3 = t ^ (4 * (lane + 192));
            acc_pt += w_lds[__popc(x0)]     * y0.x + w_lds[__popc(x0 ^ 1)] * y0.y
                    + w_lds[__popc(x0 ^ 2)] * y0.z + w_lds[__popc(x0 ^ 3)] * y0.w
                    + w_lds[__popc(x1)]     * y1.x + w_lds[__popc(x1 ^ 1)] * y1.y
                    + w_lds[__popc(x1 ^ 2)] * y1.z + w_lds[__popc(x1 ^ 3)] * y1.w
                    + w_lds[__popc(x2)]     * y2.x + w_lds[__popc(x2 ^ 1)] * y2.y
                    + w_lds[__popc(x2 ^ 2)] * y2.z + w_lds[__popc(x2 ^ 3)] * y2.w
                    + w_lds[__popc(x3)]     * y3.x + w_lds[__popc(x3 ^ 1)] * y3.y
                    + w_lds[__popc(x3 ^ 2)] * y3.z + w_lds[__popc(x3 ^ 3)] * y3.w;
            if (((t >> 2) & 63) == lane)
                acc_lg += logf(pick16(y0, y1, y2, y3, t) + 1e-8f);
        }
    }

    // single per-wave reduction at the end
    const float invB  = 1.0f / (float)B_ROWS;
    const float invBN = 1.0f / ((float)B_ROWS * (float)N_COLS);
    float val = acc_pt * invBN - acc_lg * invB;
    #pragma unroll
    for (int m = 32; m >= 1; m >>= 1) val += __shfl_xor(val, m, 64);

    if (lane == 0) wave_part[wid] = val;
    __syncthreads();
    if (tid == 0) {
        float s = 0.0f;
        #pragma unroll
        for (int w = 0; w < WAVES_PER_BLOCK; ++w) s += wave_part[w];
        atomicAdd(out, s);   // 2048 adds; reorder noise ~1e-1 << threshold 2764
    }
}

extern "C" void kernel_launch(void* const* d_in, const int* in_sizes, int n_in,
                              void* d_out, int out_size, void* d_ws, size_t ws_size,
                              hipStream_t stream) {
    const float* y_true = (const float*)d_in[0];
    const float* target = (const float*)d_in[1];
    float* out = (float*)d_out;

    hipMemsetAsync(out, 0, sizeof(float), stream);  // graph-capturable
    ce_rows_kernel<<<ROWS_BLOCKS, ROWS_THREADS, 0, stream>>>(y_true, target, out);
}

// Round 7
// 119.573 us; speedup vs baseline: 1.8741x; 1.8741x over previous
//
#include <hip/hip_runtime.h>
#include <math.h>

// B=65536 rows, N=1024 cols, fp32.
//   t_b = argmax_c target[b,c]  (first-max tie-break)
//   out = mean_b(-log(y[b,t_b]+1e-8)) + sum_{b,c} w[popc(t_b^c)]*y[b,c]/(B*N), w[p]=(p==0)?0:6^p
// R5/R6 lesson: fused kernel needs t-row + y-row co-resident = 128 VGPRs -> spill or
// occupancy loss. R7: two-kernel split. K1 streams target -> t[row] (d_ws). K2 streams
// y_true with zero cross-lane ops (t is wave-uniform broadcast). Both pure streams.

#define B_ROWS 65536
#define N_COLS 1024
#define ROWS_PER_WAVE 8
#define K1_BLOCKS 2048      // 2048*4 waves * 8 rows = 65536
#define K2_BLOCKS 2048
#define K2_THREADS 256
#define K2_NT (K2_BLOCKS * K2_THREADS)           // 524288 threads
#define K2_ITERS ((B_ROWS * (N_COLS / 4)) / K2_NT)  // 16.78M float4 / 524288 = 32

__device__ __forceinline__ void amax16(float4 v0, float4 v1, float4 v2, float4 v3,
                                       int lane, float& bv, int& bi) {
    // ascending-column scan, strict > = first-index semantics within the lane
    bv = -1.0f; bi = 0;
    const int c0 = 4 * lane, c1 = 4 * (lane + 64), c2 = 4 * (lane + 128), c3 = 4 * (lane + 192);
    if (v0.x > bv) { bv = v0.x; bi = c0;     }
    if (v0.y > bv) { bv = v0.y; bi = c0 + 1; }
    if (v0.z > bv) { bv = v0.z; bi = c0 + 2; }
    if (v0.w > bv) { bv = v0.w; bi = c0 + 3; }
    if (v1.x > bv) { bv = v1.x; bi = c1;     }
    if (v1.y > bv) { bv = v1.y; bi = c1 + 1; }
    if (v1.z > bv) { bv = v1.z; bi = c1 + 2; }
    if (v1.w > bv) { bv = v1.w; bi = c1 + 3; }
    if (v2.x > bv) { bv = v2.x; bi = c2;     }
    if (v2.y > bv) { bv = v2.y; bi = c2 + 1; }
    if (v2.z > bv) { bv = v2.z; bi = c2 + 2; }
    if (v2.w > bv) { bv = v2.w; bi = c2 + 3; }
    if (v3.x > bv) { bv = v3.x; bi = c3;     }
    if (v3.y > bv) { bv = v3.y; bi = c3 + 1; }
    if (v3.z > bv) { bv = v3.z; bi = c3 + 2; }
    if (v3.w > bv) { bv = v3.w; bi = c3 + 3; }
}

// ---------------- kernel 1: per-row argmax of target ----------------
__global__ __launch_bounds__(256)
void argmax_kernel(const float* __restrict__ target, int* __restrict__ tidx) {
    const int tid   = threadIdx.x;
    const int lane  = tid & 63;
    const int gwave = (blockIdx.x * 256 + tid) >> 6;   // 8192 waves
    const int row0  = gwave * ROWS_PER_WAVE;           // 8 consecutive rows per wave

    #pragma unroll 1
    for (int s = 0; s < ROWS_PER_WAVE; ++s) {
        const int row = row0 + s;
        const float4* tp = (const float4*)(target + (size_t)row * N_COLS);
        const float4 v0 = tp[lane], v1 = tp[lane + 64], v2 = tp[lane + 128], v3 = tp[lane + 192];
        float bv; int bi;
        amax16(v0, v1, v2, v3, lane, bv, bi);
        #pragma unroll
        for (int m = 32; m >= 1; m >>= 1) {
            const float ov = __shfl_xor(bv, m, 64);
            const int   oi = __shfl_xor(bi, m, 64);
            if (ov > bv || (ov == bv && oi < bi)) { bv = ov; bi = oi; }
        }
        if (lane == 0) tidx[row] = bi;
    }
}

// ---------------- kernel 2: weighted stream over y_true ----------------
__global__ __launch_bounds__(K2_THREADS)
void weighted_kernel(const float* __restrict__ y_true,
                     const int* __restrict__ tidx,
                     float* __restrict__ out) {
    __shared__ float w_lds[16];
    __shared__ float wave_part[K2_THREADS / 64];

    const int tid = threadIdx.x;
    if (tid < 16) {
        float w = 1.0f;
        for (int p = 0; p < tid; ++p) w *= 6.0f;   // exact: 6^10 < 2^26
        w_lds[tid] = (tid == 0) ? 0.0f : w;
    }
    __syncthreads();

    const int lane = tid & 63;
    const int wid  = tid >> 6;
    const int gtid = blockIdx.x * K2_THREADS + tid;
    const float4* y4 = (const float4*)y_true;

    float acc_pt = 0.0f;
    float acc_lg = 0.0f;

    #pragma unroll 1
    for (int it = 0; it < K2_ITERS; ++it) {
        const int i   = gtid + it * K2_NT;   // float4 index; lanes consecutive -> coalesced
        const int row = i >> 8;              // 256 float4 per row; wave-uniform (64 | 256)
        const int c0  = (i & 255) << 2;      // first column of this float4
        const float4 v = y4[i];
        const int t = tidx[row];             // same addr across wave -> broadcast, L2-hot
        const int x = t ^ c0;                // c0 % 4 == 0 -> keys x, x^1, x^2, x^3
        acc_pt += w_lds[__popc(x)]     * v.x + w_lds[__popc(x ^ 1)] * v.y
                + w_lds[__popc(x ^ 2)] * v.z + w_lds[__popc(x ^ 3)] * v.w;
        if ((t & ~3) == c0) {                // this thread owns column t: CE term
            const int e = t & 3;
            const float yt = (e & 2) ? ((e & 1) ? v.w : v.z) : ((e & 1) ? v.y : v.x);
            acc_lg += logf(yt + 1e-8f);
        }
    }

    const float invB  = 1.0f / (float)B_ROWS;
    const float invBN = 1.0f / ((float)B_ROWS * (float)N_COLS);
    float val = acc_pt * invBN - acc_lg * invB;
    #pragma unroll
    for (int m = 32; m >= 1; m >>= 1) val += __shfl_xor(val, m, 64);

    if (lane == 0) wave_part[wid] = val;
    __syncthreads();
    if (tid == 0) {
        float s = 0.0f;
        #pragma unroll
        for (int w = 0; w < K2_THREADS / 64; ++w) s += wave_part[w];
        atomicAdd(out, s);   // 2048 adds; reorder noise ~0.1 << threshold 2764
    }
}

extern "C" void kernel_launch(void* const* d_in, const int* in_sizes, int n_in,
                              void* d_out, int out_size, void* d_ws, size_t ws_size,
                              hipStream_t stream) {
    const float* y_true = (const float*)d_in[0];
    const float* target = (const float*)d_in[1];
    float* out = (float*)d_out;
    int* tidx  = (int*)d_ws;   // 65536 ints = 256 KB scratch

    hipMemsetAsync(out, 0, sizeof(float), stream);
    argmax_kernel<<<K1_BLOCKS, 256, 0, stream>>>(target, tidx);
    weighted_kernel<<<K2_BLOCKS, K2_THREADS, 0, stream>>>(y_true, tidx, out);
}